// Round 2
// baseline (17443.120 us; speedup 1.0000x reference)
//
#include <hip/hip_runtime.h>
#include <hip/hip_bf16.h>

typedef __attribute__((ext_vector_type(8))) short shortx8;
typedef __attribute__((ext_vector_type(4))) float f32x4;
typedef __attribute__((ext_vector_type(4))) unsigned short ushortx4;

#define HDIM 512
#define DDIM 64
#define TSTEPS 512
#define NSLICE 16   // batch slices
#define NB 16       // batch per slice

__device__ __forceinline__ unsigned short f2b(float f) {
    __hip_bfloat16 h = __float2bfloat16(f);
    return *reinterpret_cast<unsigned short*>(&h);
}
__device__ __forceinline__ float b2f(unsigned short s) {
    union { unsigned int u; float f; } cvt;
    cvt.u = ((unsigned int)s) << 16;
    return cvt.f;
}
__device__ __forceinline__ float fast_tanh(float v) {
    float e = __expf(2.f * v);                       // v_exp_f32 path; inf/0 at extremes -> +/-1
    return 1.f - 2.f * __builtin_amdgcn_rcpf(e + 1.f);
}

// ---------------------------------------------------------------------------
// Prep: swizzle weights into MFMA fragment-major bf16 order.
// A-fragment (16x16x32): lane l supplies A[row = l&15][k = (l>>4)*8 + j], j=0..7.
// Chunk (mtile, kblk) = 64 lanes * 16B = 1KB contiguous.
// whh0_sw: [m=32][kb=16][lane=64][8]
// w1_sw:   [m=32][kb=32][lane=64][8]   rows x K=1024 (= [w_ih1 | w_hh1])
// wih0_sw: [m=32][kb=2 ][lane=64][8]
// ---------------------------------------------------------------------------
__global__ void prep_kernel(const float* __restrict__ w_ih0, const float* __restrict__ w_hh0,
                            const float* __restrict__ w_ih1, const float* __restrict__ w_hh1,
                            const float* __restrict__ b_ih0, const float* __restrict__ b_hh0,
                            const float* __restrict__ b_ih1, const float* __restrict__ b_hh1,
                            unsigned short* __restrict__ whh0_sw,
                            unsigned short* __restrict__ w1_sw,
                            unsigned short* __restrict__ wih0_sw,
                            float* __restrict__ bias0, float* __restrict__ bias1)
{
    int idx = blockIdx.x * blockDim.x + threadIdx.x;
    int stride = gridDim.x * blockDim.x;

    for (int i = idx; i < 32 * 16 * 64; i += stride) {
        int l = i & 63, kb = (i >> 6) & 15, m = i >> 10;
        int row = m * 16 + (l & 15);
        int k0 = kb * 32 + (l >> 4) * 8;
        unsigned short* o = whh0_sw + (size_t)i * 8;
        #pragma unroll
        for (int j = 0; j < 8; ++j) o[j] = f2b(w_hh0[row * HDIM + k0 + j]);
    }
    for (int i = idx; i < 32 * 32 * 64; i += stride) {
        int l = i & 63, kb = (i >> 6) & 31, m = i >> 11;
        int row = m * 16 + (l & 15);
        int k0 = kb * 32 + (l >> 4) * 8;
        unsigned short* o = w1_sw + (size_t)i * 8;
        #pragma unroll
        for (int j = 0; j < 8; ++j) {
            int kk = k0 + j;
            float v = (kk < HDIM) ? w_ih1[row * HDIM + kk] : w_hh1[row * HDIM + (kk - HDIM)];
            o[j] = f2b(v);
        }
    }
    for (int i = idx; i < 32 * 2 * 64; i += stride) {
        int l = i & 63, kb = (i >> 6) & 1, m = i >> 7;
        int row = m * 16 + (l & 15);
        int k0 = kb * 32 + (l >> 4) * 8;
        unsigned short* o = wih0_sw + (size_t)i * 8;
        #pragma unroll
        for (int j = 0; j < 8; ++j) o[j] = f2b(w_ih0[row * DDIM + k0 + j]);
    }
    for (int i = idx; i < HDIM; i += stride) {
        bias0[i] = b_ih0[i] + b_hh0[i];
        bias1[i] = b_ih1[i] + b_hh1[i];
    }
}

// ---------------------------------------------------------------------------
// Persistent recurrent kernel: 16 WGs x 1024 threads (16 waves).
// Wave w owns M-tiles {2w, 2w+1}. h state in LDS bf16, col-major [16][512+8].
// B-fragment: lane l reads col=l&15, k=(l>>4)*8 (+kb*32).  D-fragment writes
// col=lane&15, rows (lane>>4)*4+j -> exactly the next step's B layout.
// ---------------------------------------------------------------------------
__global__ __launch_bounds__(1024, 1) void rnn_mfma(
    const float* __restrict__ x,
    const unsigned short* __restrict__ whh0_sw,
    const unsigned short* __restrict__ w1_sw,
    const unsigned short* __restrict__ wih0_sw,
    const float* __restrict__ bias0,
    const float* __restrict__ bias1,
    const float* __restrict__ w_lin,
    const float* __restrict__ b_lin,
    float* __restrict__ out)
{
    __shared__ unsigned short h1s[2][NB][HDIM + 8];
    __shared__ unsigned short h2s[2][NB][HDIM + 8];
    __shared__ unsigned short xbs[2][NB][DDIM + 8];
    __shared__ float bs0[HDIM], bs1[HDIM], wls[HDIM];

    const int tid  = threadIdx.x;
    const int w    = tid >> 6;          // wave 0..15
    const int lane = tid & 63;
    const int g    = lane >> 4;         // 0..3
    const int col  = lane & 15;
    const int bslice = blockIdx.x;

    for (int i = tid; i < HDIM; i += 1024) {
        bs0[i] = bias0[i];
        bs1[i] = bias1[i];
        wls[i] = w_lin[i];
    }
    for (int i = tid; i < NB * (HDIM + 8); i += 1024) {
        h1s[0][0][i] = 0;
        h2s[0][0][i] = 0;
    }
    {   // x(t=0)
        int bb = tid >> 6, d = tid & 63;
        float xv = x[((size_t)(bslice * NB + bb) * TSTEPS + 0) * DDIM + d];
        xbs[0][bb][d] = f2b(xv);
    }
    __syncthreads();

    const unsigned short* Ab0 = whh0_sw + (lane << 3);
    const unsigned short* Ab1 = w1_sw   + (lane << 3);
    const unsigned short* Abx = wih0_sw + (lane << 3);

#define AF(base, chunks_per_m, kb, i) \
    (*reinterpret_cast<const shortx8*>((base) + ((size_t)((2 * w + (i)) * (chunks_per_m) + (kb)) << 9)))
#define BH(hbuf, kb) \
    (*reinterpret_cast<const shortx8*>(&(hbuf)[col][(kb) * 32 + g * 8]))

    int cur = 0;
    for (int t = 0; t < TSTEPS; ++t) {
        const unsigned short (*h1c)[HDIM + 8] = h1s[cur];
        const unsigned short (*h2c)[HDIM + 8] = h2s[cur];
        unsigned short (*h1n)[HDIM + 8] = h1s[cur ^ 1];
        unsigned short (*h2n)[HDIM + 8] = h2s[cur ^ 1];

        // early x(t+1) load (LDS write deferred to just before the barrier)
        const int bb = tid >> 6, d = tid & 63;
        float xv = 0.f;
        if (t < TSTEPS - 1)
            xv = x[((size_t)(bslice * NB + bb) * TSTEPS + (t + 1)) * DDIM + d];

        // ---- layer 0: h1n = tanh(whh0 @ h1c + wih0 @ x_t + b0) ----
        f32x4 acc0, acc1;
        acc0 = *reinterpret_cast<const f32x4*>(&bs0[(2 * w + 0) * 16 + g * 4]);
        acc1 = *reinterpret_cast<const f32x4*>(&bs0[(2 * w + 1) * 16 + g * 4]);

        shortx8 a00 = AF(Ab0, 16, 0, 0), a01 = AF(Ab0, 16, 0, 1);
        shortx8 a10 = AF(Ab0, 16, 1, 0), a11 = AF(Ab0, 16, 1, 1);
        #pragma unroll
        for (int p = 0; p < 8; ++p) {
            shortx8 b0 = BH(h1c, 2 * p);
            shortx8 b1 = BH(h1c, 2 * p + 1);
            shortx8 n00, n01, n10, n11;
            if (p < 7) {
                n00 = AF(Ab0, 16, 2 * p + 2, 0); n01 = AF(Ab0, 16, 2 * p + 2, 1);
                n10 = AF(Ab0, 16, 2 * p + 3, 0); n11 = AF(Ab0, 16, 2 * p + 3, 1);
            }
            acc0 = __builtin_amdgcn_mfma_f32_16x16x32_bf16(a00, b0, acc0, 0, 0, 0);
            acc1 = __builtin_amdgcn_mfma_f32_16x16x32_bf16(a01, b0, acc1, 0, 0, 0);
            acc0 = __builtin_amdgcn_mfma_f32_16x16x32_bf16(a10, b1, acc0, 0, 0, 0);
            acc1 = __builtin_amdgcn_mfma_f32_16x16x32_bf16(a11, b1, acc1, 0, 0, 0);
            a00 = n00; a01 = n01; a10 = n10; a11 = n11;
        }
        {   // fused input projection, K=64 (kb 0,1 against xbs[cur])
            shortx8 c00 = AF(Abx, 2, 0, 0), c01 = AF(Abx, 2, 0, 1);
            shortx8 c10 = AF(Abx, 2, 1, 0), c11 = AF(Abx, 2, 1, 1);
            shortx8 xb0 = *reinterpret_cast<const shortx8*>(&xbs[cur][col][g * 8]);
            shortx8 xb1 = *reinterpret_cast<const shortx8*>(&xbs[cur][col][32 + g * 8]);
            acc0 = __builtin_amdgcn_mfma_f32_16x16x32_bf16(c00, xb0, acc0, 0, 0, 0);
            acc1 = __builtin_amdgcn_mfma_f32_16x16x32_bf16(c01, xb0, acc1, 0, 0, 0);
            acc0 = __builtin_amdgcn_mfma_f32_16x16x32_bf16(c10, xb1, acc0, 0, 0, 0);
            acc1 = __builtin_amdgcn_mfma_f32_16x16x32_bf16(c11, xb1, acc1, 0, 0, 0);
        }
        {
            ushortx4 o0, o1;
            #pragma unroll
            for (int j = 0; j < 4; ++j) {
                o0[j] = f2b(fast_tanh(acc0[j]));
                o1[j] = f2b(fast_tanh(acc1[j]));
            }
            *reinterpret_cast<ushortx4*>(&h1n[col][(2 * w + 0) * 16 + g * 4]) = o0;
            *reinterpret_cast<ushortx4*>(&h1n[col][(2 * w + 1) * 16 + g * 4]) = o1;
        }
        if (t < TSTEPS - 1) xbs[cur ^ 1][bb][d] = f2b(xv);
        __syncthreads();

        // ---- layer 1: h2n = tanh(w1cat @ [h1n; h2c] + b1), K=1024 ----
        f32x4 e0, e1;
        e0 = *reinterpret_cast<const f32x4*>(&bs1[(2 * w + 0) * 16 + g * 4]);
        e1 = *reinterpret_cast<const f32x4*>(&bs1[(2 * w + 1) * 16 + g * 4]);

        shortx8 d00 = AF(Ab1, 32, 0, 0), d01 = AF(Ab1, 32, 0, 1);
        shortx8 d10 = AF(Ab1, 32, 1, 0), d11 = AF(Ab1, 32, 1, 1);
        #pragma unroll
        for (int p = 0; p < 16; ++p) {
            const int kb0 = 2 * p, kb1 = 2 * p + 1;
            shortx8 b0 = (kb0 < 16) ? BH(h1n, kb0) : BH(h2c, kb0 - 16);
            shortx8 b1 = (kb1 < 16) ? BH(h1n, kb1) : BH(h2c, kb1 - 16);
            shortx8 n00, n01, n10, n11;
            if (p < 15) {
                n00 = AF(Ab1, 32, 2 * p + 2, 0); n01 = AF(Ab1, 32, 2 * p + 2, 1);
                n10 = AF(Ab1, 32, 2 * p + 3, 0); n11 = AF(Ab1, 32, 2 * p + 3, 1);
            }
            e0 = __builtin_amdgcn_mfma_f32_16x16x32_bf16(d00, b0, e0, 0, 0, 0);
            e1 = __builtin_amdgcn_mfma_f32_16x16x32_bf16(d01, b0, e1, 0, 0, 0);
            e0 = __builtin_amdgcn_mfma_f32_16x16x32_bf16(d10, b1, e0, 0, 0, 0);
            e1 = __builtin_amdgcn_mfma_f32_16x16x32_bf16(d11, b1, e1, 0, 0, 0);
            d00 = n00; d01 = n01; d10 = n10; d11 = n11;
        }
        {
            ushortx4 o0, o1;
            #pragma unroll
            for (int j = 0; j < 4; ++j) {
                o0[j] = f2b(fast_tanh(e0[j]));
                o1[j] = f2b(fast_tanh(e1[j]));
            }
            *reinterpret_cast<ushortx4*>(&h2n[col][(2 * w + 0) * 16 + g * 4]) = o0;
            *reinterpret_cast<ushortx4*>(&h2n[col][(2 * w + 1) * 16 + g * 4]) = o1;
        }
        __syncthreads();
        cur ^= 1;
    }

    // ---- final linear: out[b] = h2 . w_lin + b_lin ----
    {
        const unsigned short (*h2f)[HDIM + 8] = h2s[cur];
        const int b = tid >> 6;       // one wave per batch row
        float s = 0.f;
        #pragma unroll
        for (int j = 0; j < 8; ++j) {
            int k = lane + 64 * j;
            s += b2f(h2f[b][k]) * wls[k];
        }
        #pragma unroll
        for (int off = 32; off; off >>= 1) s += __shfl_xor(s, off);
        if (lane == 0) out[bslice * NB + b] = s + b_lin[0];
    }
#undef AF
#undef BH
}

extern "C" void kernel_launch(void* const* d_in, const int* in_sizes, int n_in,
                              void* d_out, int out_size, void* d_ws, size_t ws_size,
                              hipStream_t stream) {
    const float* x     = (const float*)d_in[0];
    const float* w_ih0 = (const float*)d_in[1];
    const float* w_hh0 = (const float*)d_in[2];
    const float* b_ih0 = (const float*)d_in[3];
    const float* b_hh0 = (const float*)d_in[4];
    const float* w_ih1 = (const float*)d_in[5];
    const float* w_hh1 = (const float*)d_in[6];
    const float* b_ih1 = (const float*)d_in[7];
    const float* b_hh1 = (const float*)d_in[8];
    const float* w_lin = (const float*)d_in[9];
    const float* b_lin = (const float*)d_in[10];
    float* out = (float*)d_out;

    char* ws = (char*)d_ws;
    unsigned short* whh0_sw = (unsigned short*)ws;                        // 512 KB
    unsigned short* w1_sw   = (unsigned short*)(ws + 524288);             // 1 MB
    unsigned short* wih0_sw = (unsigned short*)(ws + 524288 + 1048576);   // 64 KB
    float* bias0 = (float*)(ws + 524288 + 1048576 + 65536);               // 2 KB
    float* bias1 = (float*)(ws + 524288 + 1048576 + 65536 + 2048);        // 2 KB

    prep_kernel<<<416, 256, 0, stream>>>(w_ih0, w_hh0, w_ih1, w_hh1,
                                         b_ih0, b_hh0, b_ih1, b_hh1,
                                         whh0_sw, w1_sw, wih0_sw, bias0, bias1);
    rnn_mfma<<<NSLICE, 1024, 0, stream>>>(x, whh0_sw, w1_sw, wih0_sw,
                                          bias0, bias1, w_lin, b_lin, out);
}